// Round 11
// baseline (206.052 us; speedup 1.0000x reference)
//
#include <hip/hip_runtime.h>
#include <hip/hip_bf16.h>

#define NN 6144
#define IN_DIM 256
#define HID 64
#define HEADS 4
#define LAT 32
#define CAP 192
#define ALPHA 0.2f
#define GEMM_BLOCKS 384                  // (NN/64) * HEADS

typedef __attribute__((ext_vector_type(8))) short bf16x8;
typedef __attribute__((ext_vector_type(4))) float f32x4;

__device__ __forceinline__ float elu_f(float v)   { return v > 0.f ? v : expm1f(v); }
__device__ __forceinline__ float lrelu_f(float v) { return v > 0.f ? v : ALPHA * v; }

__device__ __forceinline__ void split_bf16(float v, unsigned short& hi, unsigned short& lo) {
    unsigned u = __builtin_bit_cast(unsigned, v);
    hi = (unsigned short)(u >> 16);
    float vh = __builtin_bit_cast(float, u & 0xFFFF0000u);
    float rl = v - vh;                       // exact
    lo = (unsigned short)(__builtin_bit_cast(unsigned, rl) >> 16);
}
__device__ __forceinline__ unsigned short f2bf(float f) {      // round-to-nearest-even
    unsigned u = __builtin_bit_cast(unsigned, f);
    return (unsigned short)((u + 0x7FFFu + ((u >> 16) & 1u)) >> 16);
}
__device__ __forceinline__ float bf2f(unsigned short b) {
    return __builtin_bit_cast(float, (unsigned)b << 16);
}

// ---------------- k_pre: gemm1(+es/ed epilogue, bf16 Wh out) blocks first, then A-scan ----------------
__global__ __launch_bounds__(256) void k_pre(const float* __restrict__ A,
                                             const float* __restrict__ x,
                                             const float* __restrict__ Wheads,
                                             const float* __restrict__ aheads,
                                             int* __restrict__ nbr, int* __restrict__ cnt,
                                             unsigned short* __restrict__ Whb,
                                             float* __restrict__ es, float* __restrict__ ed) {
    __shared__ __align__(16) float smem[2048];   // 8 KB
    int bid = blockIdx.x;
    int t = threadIdx.x;
    if (bid < GEMM_BLOCKS) {
        int head = bid & 3, m0 = (bid >> 2) * 64;
        float (*As)[64] = (float(*)[64])smem;
        float (*Bs)[64] = (float(*)[64])(smem + 1024);
        const float* Wc = Wheads + (size_t)head * IN_DIM * HID;
        int ty = t >> 4, tx = t & 15;
        float acc[4][4] = {};
        for (int k0 = 0; k0 < IN_DIM; k0 += 16) {
            {
                int row = t >> 2, k4 = (t & 3) * 4;
                float4 v = *(const float4*)(x + (size_t)(m0 + row) * IN_DIM + k0 + k4);
                As[k4 + 0][row] = v.x; As[k4 + 1][row] = v.y;
                As[k4 + 2][row] = v.z; As[k4 + 3][row] = v.w;
                int kk = t >> 4, n4 = (t & 15) * 4;
                *(float4*)&Bs[kk][n4] = *(const float4*)(Wc + (size_t)(k0 + kk) * HID + n4);
            }
            __syncthreads();
            #pragma unroll
            for (int k = 0; k < 16; ++k) {
                float4 av = *(float4*)&As[k][ty * 4];
                float4 bv = *(float4*)&Bs[k][tx * 4];
                float ar[4] = {av.x, av.y, av.z, av.w};
                float br[4] = {bv.x, bv.y, bv.z, bv.w};
                #pragma unroll
                for (int i = 0; i < 4; ++i)
                    #pragma unroll
                    for (int j = 0; j < 4; ++j)
                        acc[i][j] = fmaf(ar[i], br[j], acc[i][j]);
            }
            __syncthreads();
        }
        #pragma unroll
        for (int i = 0; i < 4; ++i) {
            ushort4 o;
            o.x = f2bf(acc[i][0]); o.y = f2bf(acc[i][1]);
            o.z = f2bf(acc[i][2]); o.w = f2bf(acc[i][3]);
            *(ushort4*)(Whb + (size_t)(m0 + ty * 4 + i) * (HEADS * HID) + head * HID + tx * 4) = o;
        }
        float4 a1v = *(const float4*)(aheads + head * 2 * HID + tx * 4);
        float4 a2v = *(const float4*)(aheads + head * 2 * HID + HID + tx * 4);
        #pragma unroll
        for (int i = 0; i < 4; ++i) {
            float p1 = acc[i][0] * a1v.x + acc[i][1] * a1v.y + acc[i][2] * a1v.z + acc[i][3] * a1v.w;
            float p2 = acc[i][0] * a2v.x + acc[i][1] * a2v.y + acc[i][2] * a2v.z + acc[i][3] * a2v.w;
            #pragma unroll
            for (int off = 8; off; off >>= 1) {
                p1 += __shfl_down(p1, off, 16);
                p2 += __shfl_down(p2, off, 16);
            }
            if (tx == 0) {
                es[head * NN + m0 + ty * 4 + i] = p1;
                ed[head * NN + m0 + ty * 4 + i] = p2;
            }
        }
    } else {
        int row = bid - GEMM_BLOCKS;
        int* lcnt = (int*)smem;
        const float4* Arow = (const float4*)(A + (size_t)row * NN);
        if (t == 0) *lcnt = 0;
        __syncthreads();
        int* my = nbr + (size_t)row * CAP;
        #pragma unroll
        for (int it = 0; it < NN / 4 / 256; ++it) {
            int idx4 = it * 256 + t;
            float4 v = Arow[idx4];
            int base = idx4 * 4;
            if (v.x != 0.f) { int p = atomicAdd(lcnt, 1); if (p < CAP) my[p] = base; }
            if (v.y != 0.f) { int p = atomicAdd(lcnt, 1); if (p < CAP) my[p] = base + 1; }
            if (v.z != 0.f) { int p = atomicAdd(lcnt, 1); if (p < CAP) my[p] = base + 2; }
            if (v.w != 0.f) { int p = atomicAdd(lcnt, 1); if (p < CAP) my[p] = base + 3; }
        }
        __syncthreads();
        if (t == 0) cnt[row] = *lcnt < CAP ? *lcnt : CAP;
    }
}

// ---------------- k_attn1g2: ATTRIBUTION BUILD — body repeated 3x (idempotent writes) ----------------
__global__ __launch_bounds__(256, 8) void k_attn1g2(const int* __restrict__ nbr, const int* __restrict__ cnt,
                                                    const float* __restrict__ es, const float* __restrict__ ed,
                                                    const unsigned short* __restrict__ Whb,
                                                    const float* __restrict__ Wout, const float* __restrict__ aout,
                                                    float* __restrict__ Wh2,
                                                    float* __restrict__ es2, float* __restrict__ ed2) {
    __shared__ int col[CAP];
    __shared__ float att[HEADS][CAP];
    __shared__ float hrow[HEADS * HID];
    __shared__ float part[8][LAT];
    int i = blockIdx.x;
    int t = threadIdx.x, h = t >> 6, l = t & 63;
    int c = cnt[i];
    for (int rep = 0; rep < 3; ++rep) {
        float hval;
        if (c == 0) {
            float s = 0.f;
            for (int r = 0; r < NN; ++r) s += bf2f(Whb[(size_t)r * (HEADS * HID) + h * HID + l]);
            hval = elu_f(s * (1.0f / NN));
        } else {
            const int* nb = nbr + (size_t)i * CAP;
            float esi = es[h * NN + i];
            float m = -3.0e38f;
            for (int j = l; j < c; j += 64) {
                int cj = nb[j];
                if (h == 0) col[j] = cj;
                float e = lrelu_f(esi + ed[h * NN + cj]);
                att[h][j] = e;
                m = fmaxf(m, e);
            }
            #pragma unroll
            for (int off = 32; off; off >>= 1) m = fmaxf(m, __shfl_down(m, off));
            m = __shfl(m, 0);
            float s = 0.f;
            for (int j = l; j < c; j += 64) {
                float p = __expf(att[h][j] - m);
                att[h][j] = p;
                s += p;
            }
            #pragma unroll
            for (int off = 32; off; off >>= 1) s += __shfl_down(s, off);
            s = __shfl(s, 0);
            __syncthreads();          // col[] + att[h][] visible to all
            float inv = 1.0f / s;
            const unsigned short* WhH = Whb + h * HID + l;
            float a0 = 0.f, a1 = 0.f, a2 = 0.f, a3 = 0.f;
            float a4 = 0.f, a5 = 0.f, a6 = 0.f, a7 = 0.f;
            int j = 0;
            for (; j + 8 <= c; j += 8) {
                a0 = fmaf(att[h][j + 0], bf2f(WhH[(size_t)col[j + 0] * (HEADS * HID)]), a0);
                a1 = fmaf(att[h][j + 1], bf2f(WhH[(size_t)col[j + 1] * (HEADS * HID)]), a1);
                a2 = fmaf(att[h][j + 2], bf2f(WhH[(size_t)col[j + 2] * (HEADS * HID)]), a2);
                a3 = fmaf(att[h][j + 3], bf2f(WhH[(size_t)col[j + 3] * (HEADS * HID)]), a3);
                a4 = fmaf(att[h][j + 4], bf2f(WhH[(size_t)col[j + 4] * (HEADS * HID)]), a4);
                a5 = fmaf(att[h][j + 5], bf2f(WhH[(size_t)col[j + 5] * (HEADS * HID)]), a5);
                a6 = fmaf(att[h][j + 6], bf2f(WhH[(size_t)col[j + 6] * (HEADS * HID)]), a6);
                a7 = fmaf(att[h][j + 7], bf2f(WhH[(size_t)col[j + 7] * (HEADS * HID)]), a7);
            }
            for (; j < c; ++j)
                a0 = fmaf(att[h][j], bf2f(WhH[(size_t)col[j] * (HEADS * HID)]), a0);
            hval = elu_f((((a0 + a1) + (a2 + a3)) + ((a4 + a5) + (a6 + a7))) * inv);
        }
        asm volatile("" : "+v"(hval));   // keep reps live (no cross-rep CSE)
        hrow[h * HID + l] = hval;
        __syncthreads();
        {
            int half = l >> 5, cc = l & 31;
            int tbase = h * HID + half * 32;
            float p = 0.f;
            #pragma unroll 8
            for (int tt = 0; tt < 32; ++tt)
                p = fmaf(hrow[tbase + tt], Wout[(tbase + tt) * LAT + cc], p);
            part[h * 2 + half][cc] = p;
        }
        __syncthreads();
        if (t < 32) {
            float acc = 0.f;
            #pragma unroll
            for (int w = 0; w < 8; ++w) acc += part[w][t];
            Wh2[(size_t)i * LAT + t] = acc;
            float p1 = acc * aout[t], p2 = acc * aout[LAT + t];
            #pragma unroll
            for (int off = 16; off; off >>= 1) {
                p1 += __shfl_down(p1, off, 32);
                p2 += __shfl_down(p2, off, 32);
            }
            if (t == 0) { es2[i] = p1; ed2[i] = p2; }
        }
        __syncthreads();   // protect LDS reuse across reps
    }
}

// ---------------- attention layer 2 -> z (split bf16 out), 4 rows per block ----------------
__global__ __launch_bounds__(256, 8) void k_attn2(const int* __restrict__ nbr, const int* __restrict__ cnt,
                                                  const float* __restrict__ es2, const float* __restrict__ ed2,
                                                  const float* __restrict__ Wh2,
                                                  unsigned short* __restrict__ zh, unsigned short* __restrict__ zl) {
    __shared__ float att[4][CAP];
    __shared__ int col[4][CAP];
    int w = threadIdx.x >> 6, l = threadIdx.x & 63;
    int i = blockIdx.x * 4 + w;
    int c = cnt[i];
    if (c == 0) {
        if (l < LAT) {
            float s = 0.f;
            for (int r = 0; r < NN; ++r) s += Wh2[(size_t)r * LAT + l];
            unsigned short hi, lo;
            split_bf16(elu_f(s * (1.0f / NN)), hi, lo);
            zh[(size_t)i * LAT + l] = hi;
            zl[(size_t)i * LAT + l] = lo;
        }
        return;
    }
    float esi = es2[i];
    const int* nb = nbr + (size_t)i * CAP;
    float m = -3.0e38f;
    for (int j = l; j < c; j += 64) {
        int cj = nb[j];
        col[w][j] = cj;
        float e = lrelu_f(esi + ed2[cj]);
        att[w][j] = e;
        m = fmaxf(m, e);
    }
    #pragma unroll
    for (int off = 32; off; off >>= 1) m = fmaxf(m, __shfl_down(m, off));
    m = __shfl(m, 0);
    float s = 0.f;
    for (int j = l; j < c; j += 64) {
        float p = __expf(att[w][j] - m);
        att[w][j] = p;
        s += p;
    }
    #pragma unroll
    for (int off = 32; off; off >>= 1) s += __shfl_down(s, off);
    s = __shfl(s, 0);
    if (l < LAT) {
        float inv = 1.0f / s;
        float a0 = 0.f, a1 = 0.f, a2 = 0.f, a3 = 0.f;
        int j = 0;
        for (; j + 4 <= c; j += 4) {
            a0 = fmaf(att[w][j + 0], Wh2[(size_t)col[w][j + 0] * LAT + l], a0);
            a1 = fmaf(att[w][j + 1], Wh2[(size_t)col[w][j + 1] * LAT + l], a1);
            a2 = fmaf(att[w][j + 2], Wh2[(size_t)col[w][j + 2] * LAT + l], a2);
            a3 = fmaf(att[w][j + 3], Wh2[(size_t)col[w][j + 3] * LAT + l], a3);
        }
        for (; j < c; ++j)
            a0 = fmaf(att[w][j], Wh2[(size_t)col[w][j] * LAT + l], a0);
        unsigned short hi, lo;
        split_bf16(elu_f(((a0 + a1) + (a2 + a3)) * inv), hi, lo);
        zh[(size_t)i * LAT + l] = hi;
        zl[(size_t)i * LAT + l] = lo;
    }
}

// ---------------- out = sigmoid(z @ z^T) via split-bf16 MFMA, symmetric float4 stores ----------------
__global__ __launch_bounds__(256, 8) void k_zzt(const unsigned short* __restrict__ zh,
                                                const unsigned short* __restrict__ zl,
                                                float* __restrict__ out) {
    int t = threadIdx.x, w = t >> 6, l = t & 63;
    int m0 = blockIdx.y * 64 + w * 16;
    int n0 = blockIdx.x * 64;
    int r = l & 15, kg = (l >> 4) * 8;   // lane row-in-tile, k-group of 8
    bf16x8 ah = *(const bf16x8*)(zh + (size_t)(m0 + r) * LAT + kg);
    bf16x8 al = *(const bf16x8*)(zl + (size_t)(m0 + r) * LAT + kg);
    int mbase = m0 + (l >> 4) * 4;       // 4 consecutive C-rows this lane owns
    #pragma unroll
    for (int jp = 0; jp < 2; ++jp) {
        int nbA = n0 + (jp * 2 + 0) * 16;
        int nbB = n0 + (jp * 2 + 1) * 16;
        bf16x8 bhA = *(const bf16x8*)(zh + (size_t)(nbA + r) * LAT + kg);
        bf16x8 blA = *(const bf16x8*)(zl + (size_t)(nbA + r) * LAT + kg);
        bf16x8 bhB = *(const bf16x8*)(zh + (size_t)(nbB + r) * LAT + kg);
        bf16x8 blB = *(const bf16x8*)(zl + (size_t)(nbB + r) * LAT + kg);
        f32x4 accA = {0.f, 0.f, 0.f, 0.f};
        accA = __builtin_amdgcn_mfma_f32_16x16x32_bf16(ah, bhA, accA, 0, 0, 0);
        accA = __builtin_amdgcn_mfma_f32_16x16x32_bf16(ah, blA, accA, 0, 0, 0);
        accA = __builtin_amdgcn_mfma_f32_16x16x32_bf16(al, bhA, accA, 0, 0, 0);
        f32x4 accB = {0.f, 0.f, 0.f, 0.f};
        accB = __builtin_amdgcn_mfma_f32_16x16x32_bf16(ah, bhB, accB, 0, 0, 0);
        accB = __builtin_amdgcn_mfma_f32_16x16x32_bf16(ah, blB, accB, 0, 0, 0);
        accB = __builtin_amdgcn_mfma_f32_16x16x32_bf16(al, bhB, accB, 0, 0, 0);
        float4 oA, oB;
        oA.x = 1.0f / (1.0f + __expf(-accA[0]));
        oA.y = 1.0f / (1.0f + __expf(-accA[1]));
        oA.z = 1.0f / (1.0f + __expf(-accA[2]));
        oA.w = 1.0f / (1.0f + __expf(-accA[3]));
        oB.x = 1.0f / (1.0f + __expf(-accB[0]));
        oB.y = 1.0f / (1.0f + __expf(-accB[1]));
        oB.z = 1.0f / (1.0f + __expf(-accB[2]));
        oB.w = 1.0f / (1.0f + __expf(-accB[3]));
        // transposed store via output symmetry: out[col][mbase..mbase+3]
        *(float4*)(out + (size_t)(nbA + (l & 15)) * NN + mbase) = oA;
        *(float4*)(out + (size_t)(nbB + (l & 15)) * NN + mbase) = oB;
    }
}

extern "C" void kernel_launch(void* const* d_in, const int* in_sizes, int n_in,
                              void* d_out, int out_size, void* d_ws, size_t ws_size,
                              hipStream_t stream) {
    const float* x      = (const float*)d_in[0];
    const float* A      = (const float*)d_in[1];
    const float* Wheads = (const float*)d_in[2];
    const float* aheads = (const float*)d_in[3];
    const float* Wout   = (const float*)d_in[4];
    const float* aout   = (const float*)d_in[5];
    float* out = (float*)d_out;

    char* ws = (char*)d_ws;
    size_t o = 0;
    auto alloc = [&](size_t bytes) { void* p = ws + o; o += (bytes + 255) & ~(size_t)255; return p; };
    int*   nbr   = (int*)  alloc((size_t)NN * CAP * 4);
    int*   cnt   = (int*)  alloc((size_t)NN * 4);
    unsigned short* Whb = (unsigned short*)alloc((size_t)NN * HEADS * HID * 2);
    float* es    = (float*)alloc((size_t)HEADS * NN * 4);
    float* ed    = (float*)alloc((size_t)HEADS * NN * 4);
    float* Wh2   = (float*)alloc((size_t)NN * LAT * 4);
    float* es2   = (float*)alloc((size_t)NN * 4);
    float* ed2   = (float*)alloc((size_t)NN * 4);
    unsigned short* zh = (unsigned short*)alloc((size_t)NN * LAT * 2);
    unsigned short* zl = (unsigned short*)alloc((size_t)NN * LAT * 2);

    k_pre     <<<GEMM_BLOCKS + NN, 256, 0, stream>>>(A, x, Wheads, aheads, nbr, cnt, Whb, es, ed);
    k_attn1g2 <<<NN, 256, 0, stream>>>(nbr, cnt, es, ed, Whb, Wout, aout, Wh2, es2, ed2);
    k_attn2   <<<NN / 4, 256, 0, stream>>>(nbr, cnt, es2, ed2, Wh2, zh, zl);
    k_zzt     <<<dim3(NN / 64, NN / 64), 256, 0, stream>>>(zh, zl, out);
}

// Round 12
// 114.540 us; speedup vs baseline: 1.7990x; 1.7990x over previous
//
#include <hip/hip_runtime.h>
#include <hip/hip_bf16.h>

#define NN 6144
#define IN_DIM 256
#define HID 64
#define HEADS 4
#define LAT 32
#define CAP 192
#define ALPHA 0.2f
#define GEMM_BLOCKS 384                  // (NN/64) * HEADS

typedef __attribute__((ext_vector_type(8))) short bf16x8;
typedef __attribute__((ext_vector_type(4))) float f32x4;

__device__ __forceinline__ float elu_f(float v)   { return v > 0.f ? v : expm1f(v); }
__device__ __forceinline__ float lrelu_f(float v) { return v > 0.f ? v : ALPHA * v; }

__device__ __forceinline__ void split_bf16(float v, unsigned short& hi, unsigned short& lo) {
    unsigned u = __builtin_bit_cast(unsigned, v);
    hi = (unsigned short)(u >> 16);
    float vh = __builtin_bit_cast(float, u & 0xFFFF0000u);
    float rl = v - vh;                       // exact
    lo = (unsigned short)(__builtin_bit_cast(unsigned, rl) >> 16);
}
__device__ __forceinline__ unsigned short f2bf(float f) {      // round-to-nearest-even
    unsigned u = __builtin_bit_cast(unsigned, f);
    return (unsigned short)((u + 0x7FFFu + ((u >> 16) & 1u)) >> 16);
}
__device__ __forceinline__ float bf2f(unsigned short b) {
    return __builtin_bit_cast(float, (unsigned)b << 16);
}

// ---------------- k_pre: gemm1(+es4/ed4 epilogue, bf16 Wh out) blocks first, then A-scan ----------------
__global__ __launch_bounds__(256) void k_pre(const float* __restrict__ A,
                                             const float* __restrict__ x,
                                             const float* __restrict__ Wheads,
                                             const float* __restrict__ aheads,
                                             int* __restrict__ nbr, int* __restrict__ cnt,
                                             unsigned short* __restrict__ Whb,
                                             float* __restrict__ es4, float* __restrict__ ed4) {
    __shared__ __align__(16) float smem[2048];   // 8 KB
    int bid = blockIdx.x;
    int t = threadIdx.x;
    if (bid < GEMM_BLOCKS) {
        int head = bid & 3, m0 = (bid >> 2) * 64;
        float (*As)[64] = (float(*)[64])smem;
        float (*Bs)[64] = (float(*)[64])(smem + 1024);
        const float* Wc = Wheads + (size_t)head * IN_DIM * HID;
        int ty = t >> 4, tx = t & 15;
        float acc[4][4] = {};
        for (int k0 = 0; k0 < IN_DIM; k0 += 16) {
            {
                int row = t >> 2, k4 = (t & 3) * 4;
                float4 v = *(const float4*)(x + (size_t)(m0 + row) * IN_DIM + k0 + k4);
                As[k4 + 0][row] = v.x; As[k4 + 1][row] = v.y;
                As[k4 + 2][row] = v.z; As[k4 + 3][row] = v.w;
                int kk = t >> 4, n4 = (t & 15) * 4;
                *(float4*)&Bs[kk][n4] = *(const float4*)(Wc + (size_t)(k0 + kk) * HID + n4);
            }
            __syncthreads();
            #pragma unroll
            for (int k = 0; k < 16; ++k) {
                float4 av = *(float4*)&As[k][ty * 4];
                float4 bv = *(float4*)&Bs[k][tx * 4];
                float ar[4] = {av.x, av.y, av.z, av.w};
                float br[4] = {bv.x, bv.y, bv.z, bv.w};
                #pragma unroll
                for (int i = 0; i < 4; ++i)
                    #pragma unroll
                    for (int j = 0; j < 4; ++j)
                        acc[i][j] = fmaf(ar[i], br[j], acc[i][j]);
            }
            __syncthreads();
        }
        #pragma unroll
        for (int i = 0; i < 4; ++i) {
            ushort4 o;
            o.x = f2bf(acc[i][0]); o.y = f2bf(acc[i][1]);
            o.z = f2bf(acc[i][2]); o.w = f2bf(acc[i][3]);
            *(ushort4*)(Whb + (size_t)(m0 + ty * 4 + i) * (HEADS * HID) + head * HID + tx * 4) = o;
        }
        float4 a1v = *(const float4*)(aheads + head * 2 * HID + tx * 4);
        float4 a2v = *(const float4*)(aheads + head * 2 * HID + HID + tx * 4);
        #pragma unroll
        for (int i = 0; i < 4; ++i) {
            float p1 = acc[i][0] * a1v.x + acc[i][1] * a1v.y + acc[i][2] * a1v.z + acc[i][3] * a1v.w;
            float p2 = acc[i][0] * a2v.x + acc[i][1] * a2v.y + acc[i][2] * a2v.z + acc[i][3] * a2v.w;
            #pragma unroll
            for (int off = 8; off; off >>= 1) {
                p1 += __shfl_down(p1, off, 16);
                p2 += __shfl_down(p2, off, 16);
            }
            if (tx == 0) {
                es4[(size_t)(m0 + ty * 4 + i) * 4 + head] = p1;   // [row][head]
                ed4[(size_t)(m0 + ty * 4 + i) * 4 + head] = p2;
            }
        }
    } else {
        int row = bid - GEMM_BLOCKS;
        int* lcnt = (int*)smem;
        const float4* Arow = (const float4*)(A + (size_t)row * NN);
        if (t == 0) *lcnt = 0;
        __syncthreads();
        int* my = nbr + (size_t)row * CAP;
        #pragma unroll
        for (int it = 0; it < NN / 4 / 256; ++it) {
            int idx4 = it * 256 + t;
            float4 v = Arow[idx4];
            int base = idx4 * 4;
            if (v.x != 0.f) { int p = atomicAdd(lcnt, 1); if (p < CAP) my[p] = base; }
            if (v.y != 0.f) { int p = atomicAdd(lcnt, 1); if (p < CAP) my[p] = base + 1; }
            if (v.z != 0.f) { int p = atomicAdd(lcnt, 1); if (p < CAP) my[p] = base + 2; }
            if (v.w != 0.f) { int p = atomicAdd(lcnt, 1); if (p < CAP) my[p] = base + 3; }
        }
        __syncthreads();
        if (t == 0) cnt[row] = *lcnt < CAP ? *lcnt : CAP;
    }
}

// ---------------- k_attn1g2: 4 rows/block, ONE WAVE PER ROW covers all 4 heads ----------------
// Lane l owns Whb columns 4l..4l+3 (head = l>>4). PV gather = one 8B ushort4 per lane.
__global__ __launch_bounds__(256, 8) void k_attn1g2(const int* __restrict__ nbr, const int* __restrict__ cnt,
                                                    const float4* __restrict__ es4, const float4* __restrict__ ed4,
                                                    const unsigned short* __restrict__ Whb,
                                                    const float* __restrict__ Wout, const float* __restrict__ aout,
                                                    float* __restrict__ Wh2,
                                                    float* __restrict__ es2, float* __restrict__ ed2) {
    __shared__ int colS[4][CAP];                 // 3 KB
    __shared__ __align__(16) float att4[4][CAP][4];  // [row][j][head] 12 KB
    __shared__ __align__(16) float hrow[4][HEADS * HID]; // 4 KB
    int w = threadIdx.x >> 6, l = threadIdx.x & 63;
    int i = blockIdx.x * 4 + w;
    int c = cnt[i];
    const int* nb = nbr + (size_t)i * CAP;

    // phase 1: neighbor list + e (all 4 heads per lane), track per-head max
    float4 esv = es4[i];
    float m0 = -3.0e38f, m1 = -3.0e38f, m2 = -3.0e38f, m3 = -3.0e38f;
    for (int j = l; j < c; j += 64) {
        int cj = nb[j];
        colS[w][j] = cj;
        float4 edv = ed4[cj];
        float4 e;
        e.x = lrelu_f(esv.x + edv.x); e.y = lrelu_f(esv.y + edv.y);
        e.z = lrelu_f(esv.z + edv.z); e.w = lrelu_f(esv.w + edv.w);
        *(float4*)&att4[w][j][0] = e;
        m0 = fmaxf(m0, e.x); m1 = fmaxf(m1, e.y);
        m2 = fmaxf(m2, e.z); m3 = fmaxf(m3, e.w);
    }
    #pragma unroll
    for (int off = 32; off; off >>= 1) {
        m0 = fmaxf(m0, __shfl_down(m0, off)); m1 = fmaxf(m1, __shfl_down(m1, off));
        m2 = fmaxf(m2, __shfl_down(m2, off)); m3 = fmaxf(m3, __shfl_down(m3, off));
    }
    m0 = __shfl(m0, 0); m1 = __shfl(m1, 0); m2 = __shfl(m2, 0); m3 = __shfl(m3, 0);
    // phase 2: exp + per-head sum (same-lane LDS entries)
    float s0 = 0.f, s1 = 0.f, s2 = 0.f, s3 = 0.f;
    for (int j = l; j < c; j += 64) {
        float4 e = *(float4*)&att4[w][j][0];
        e.x = __expf(e.x - m0); e.y = __expf(e.y - m1);
        e.z = __expf(e.z - m2); e.w = __expf(e.w - m3);
        *(float4*)&att4[w][j][0] = e;
        s0 += e.x; s1 += e.y; s2 += e.z; s3 += e.w;
    }
    #pragma unroll
    for (int off = 32; off; off >>= 1) {
        s0 += __shfl_down(s0, off); s1 += __shfl_down(s1, off);
        s2 += __shfl_down(s2, off); s3 += __shfl_down(s3, off);
    }
    s0 = __shfl(s0, 0); s1 = __shfl(s1, 0); s2 = __shfl(s2, 0); s3 = __shfl(s3, 0);
    __syncthreads();   // att4/colS visible (cross-lane)

    // phase 3: PV — lane l gathers ushort4 (cols 4l..4l+3) per neighbor
    int hd = l >> 4;
    float sh = hd < 2 ? (hd == 0 ? s0 : s1) : (hd == 2 ? s2 : s3);
    float invh = 1.0f / sh;
    float4 hv;
    if (c == 0) {   // deg==0 fallback: column means (never taken w.h.p.)
        float a0 = 0.f, a1 = 0.f, a2 = 0.f, a3 = 0.f;
        for (int r = 0; r < NN; ++r) {
            ushort4 v = *(const ushort4*)(Whb + (size_t)r * (HEADS * HID) + 4 * l);
            a0 += bf2f(v.x); a1 += bf2f(v.y); a2 += bf2f(v.z); a3 += bf2f(v.w);
        }
        hv.x = elu_f(a0 / NN); hv.y = elu_f(a1 / NN);
        hv.z = elu_f(a2 / NN); hv.w = elu_f(a3 / NN);
    } else {
        const unsigned short* Wb = Whb + 4 * l;
        float aA0 = 0.f, aA1 = 0.f, aA2 = 0.f, aA3 = 0.f;
        float aB0 = 0.f, aB1 = 0.f, aB2 = 0.f, aB3 = 0.f;
        int j = 0;
        for (; j + 2 <= c; j += 2) {
            int cjA = colS[w][j], cjB = colS[w][j + 1];
            float fA = att4[w][j][hd], fB = att4[w][j + 1][hd];
            ushort4 vA = *(const ushort4*)(Wb + (size_t)cjA * (HEADS * HID));
            ushort4 vB = *(const ushort4*)(Wb + (size_t)cjB * (HEADS * HID));
            aA0 = fmaf(fA, bf2f(vA.x), aA0); aA1 = fmaf(fA, bf2f(vA.y), aA1);
            aA2 = fmaf(fA, bf2f(vA.z), aA2); aA3 = fmaf(fA, bf2f(vA.w), aA3);
            aB0 = fmaf(fB, bf2f(vB.x), aB0); aB1 = fmaf(fB, bf2f(vB.y), aB1);
            aB2 = fmaf(fB, bf2f(vB.z), aB2); aB3 = fmaf(fB, bf2f(vB.w), aB3);
        }
        if (j < c) {
            int cj = colS[w][j];
            float f = att4[w][j][hd];
            ushort4 v = *(const ushort4*)(Wb + (size_t)cj * (HEADS * HID));
            aA0 = fmaf(f, bf2f(v.x), aA0); aA1 = fmaf(f, bf2f(v.y), aA1);
            aA2 = fmaf(f, bf2f(v.z), aA2); aA3 = fmaf(f, bf2f(v.w), aA3);
        }
        hv.x = elu_f((aA0 + aB0) * invh); hv.y = elu_f((aA1 + aB1) * invh);
        hv.z = elu_f((aA2 + aB2) * invh); hv.w = elu_f((aA3 + aB3) * invh);
    }
    *(float4*)&hrow[w][4 * l] = hv;
    __syncthreads();

    // phase 4: gemm2 — wave w computes Wh2[i,:]; 2 lanes per col, 128-deep each
    {
        int half = l >> 5, cc = l & 31;
        int tbase = half * 128;
        float p = 0.f;
        #pragma unroll 8
        for (int tt = 0; tt < 128; ++tt)
            p = fmaf(hrow[w][tbase + tt], Wout[(tbase + tt) * LAT + cc], p);
        p += __shfl_down(p, 32);
        if (l < 32) {
            Wh2[(size_t)i * LAT + cc] = p;
            float p1 = p * aout[cc], p2 = p * aout[LAT + cc];
            #pragma unroll
            for (int off = 16; off; off >>= 1) {
                p1 += __shfl_down(p1, off, 32);
                p2 += __shfl_down(p2, off, 32);
            }
            if (cc == 0) { es2[i] = p1; ed2[i] = p2; }
        }
    }
}

// ---------------- attention layer 2 -> z (split bf16 out), 4 rows per block ----------------
__global__ __launch_bounds__(256, 8) void k_attn2(const int* __restrict__ nbr, const int* __restrict__ cnt,
                                                  const float* __restrict__ es2, const float* __restrict__ ed2,
                                                  const float* __restrict__ Wh2,
                                                  unsigned short* __restrict__ zh, unsigned short* __restrict__ zl) {
    __shared__ float att[4][CAP];
    __shared__ int col[4][CAP];
    int w = threadIdx.x >> 6, l = threadIdx.x & 63;
    int i = blockIdx.x * 4 + w;
    int c = cnt[i];
    if (c == 0) {
        if (l < LAT) {
            float s = 0.f;
            for (int r = 0; r < NN; ++r) s += Wh2[(size_t)r * LAT + l];
            unsigned short hi, lo;
            split_bf16(elu_f(s * (1.0f / NN)), hi, lo);
            zh[(size_t)i * LAT + l] = hi;
            zl[(size_t)i * LAT + l] = lo;
        }
        return;
    }
    float esi = es2[i];
    const int* nb = nbr + (size_t)i * CAP;
    float m = -3.0e38f;
    for (int j = l; j < c; j += 64) {
        int cj = nb[j];
        col[w][j] = cj;
        float e = lrelu_f(esi + ed2[cj]);
        att[w][j] = e;
        m = fmaxf(m, e);
    }
    #pragma unroll
    for (int off = 32; off; off >>= 1) m = fmaxf(m, __shfl_down(m, off));
    m = __shfl(m, 0);
    float s = 0.f;
    for (int j = l; j < c; j += 64) {
        float p = __expf(att[w][j] - m);
        att[w][j] = p;
        s += p;
    }
    #pragma unroll
    for (int off = 32; off; off >>= 1) s += __shfl_down(s, off);
    s = __shfl(s, 0);
    if (l < LAT) {
        float inv = 1.0f / s;
        float a0 = 0.f, a1 = 0.f, a2 = 0.f, a3 = 0.f;
        int j = 0;
        for (; j + 4 <= c; j += 4) {
            a0 = fmaf(att[w][j + 0], Wh2[(size_t)col[w][j + 0] * LAT + l], a0);
            a1 = fmaf(att[w][j + 1], Wh2[(size_t)col[w][j + 1] * LAT + l], a1);
            a2 = fmaf(att[w][j + 2], Wh2[(size_t)col[w][j + 2] * LAT + l], a2);
            a3 = fmaf(att[w][j + 3], Wh2[(size_t)col[w][j + 3] * LAT + l], a3);
        }
        for (; j < c; ++j)
            a0 = fmaf(att[w][j], Wh2[(size_t)col[w][j] * LAT + l], a0);
        unsigned short hi, lo;
        split_bf16(elu_f(((a0 + a1) + (a2 + a3)) * inv), hi, lo);
        zh[(size_t)i * LAT + l] = hi;
        zl[(size_t)i * LAT + l] = lo;
    }
}

// ---------------- out = sigmoid(z @ z^T) via split-bf16 MFMA, symmetric float4 stores ----------------
__global__ __launch_bounds__(256, 8) void k_zzt(const unsigned short* __restrict__ zh,
                                                const unsigned short* __restrict__ zl,
                                                float* __restrict__ out) {
    int t = threadIdx.x, w = t >> 6, l = t & 63;
    int m0 = blockIdx.y * 64 + w * 16;
    int n0 = blockIdx.x * 64;
    int r = l & 15, kg = (l >> 4) * 8;   // lane row-in-tile, k-group of 8
    bf16x8 ah = *(const bf16x8*)(zh + (size_t)(m0 + r) * LAT + kg);
    bf16x8 al = *(const bf16x8*)(zl + (size_t)(m0 + r) * LAT + kg);
    int mbase = m0 + (l >> 4) * 4;       // 4 consecutive C-rows this lane owns
    #pragma unroll
    for (int jp = 0; jp < 2; ++jp) {
        int nbA = n0 + (jp * 2 + 0) * 16;
        int nbB = n0 + (jp * 2 + 1) * 16;
        bf16x8 bhA = *(const bf16x8*)(zh + (size_t)(nbA + r) * LAT + kg);
        bf16x8 blA = *(const bf16x8*)(zl + (size_t)(nbA + r) * LAT + kg);
        bf16x8 bhB = *(const bf16x8*)(zh + (size_t)(nbB + r) * LAT + kg);
        bf16x8 blB = *(const bf16x8*)(zl + (size_t)(nbB + r) * LAT + kg);
        f32x4 accA = {0.f, 0.f, 0.f, 0.f};
        accA = __builtin_amdgcn_mfma_f32_16x16x32_bf16(ah, bhA, accA, 0, 0, 0);
        accA = __builtin_amdgcn_mfma_f32_16x16x32_bf16(ah, blA, accA, 0, 0, 0);
        accA = __builtin_amdgcn_mfma_f32_16x16x32_bf16(al, bhA, accA, 0, 0, 0);
        f32x4 accB = {0.f, 0.f, 0.f, 0.f};
        accB = __builtin_amdgcn_mfma_f32_16x16x32_bf16(ah, bhB, accB, 0, 0, 0);
        accB = __builtin_amdgcn_mfma_f32_16x16x32_bf16(ah, blB, accB, 0, 0, 0);
        accB = __builtin_amdgcn_mfma_f32_16x16x32_bf16(al, bhB, accB, 0, 0, 0);
        float4 oA, oB;
        oA.x = 1.0f / (1.0f + __expf(-accA[0]));
        oA.y = 1.0f / (1.0f + __expf(-accA[1]));
        oA.z = 1.0f / (1.0f + __expf(-accA[2]));
        oA.w = 1.0f / (1.0f + __expf(-accA[3]));
        oB.x = 1.0f / (1.0f + __expf(-accB[0]));
        oB.y = 1.0f / (1.0f + __expf(-accB[1]));
        oB.z = 1.0f / (1.0f + __expf(-accB[2]));
        oB.w = 1.0f / (1.0f + __expf(-accB[3]));
        // transposed store via output symmetry: out[col][mbase..mbase+3]
        *(float4*)(out + (size_t)(nbA + (l & 15)) * NN + mbase) = oA;
        *(float4*)(out + (size_t)(nbB + (l & 15)) * NN + mbase) = oB;
    }
}

extern "C" void kernel_launch(void* const* d_in, const int* in_sizes, int n_in,
                              void* d_out, int out_size, void* d_ws, size_t ws_size,
                              hipStream_t stream) {
    const float* x      = (const float*)d_in[0];
    const float* A      = (const float*)d_in[1];
    const float* Wheads = (const float*)d_in[2];
    const float* aheads = (const float*)d_in[3];
    const float* Wout   = (const float*)d_in[4];
    const float* aout   = (const float*)d_in[5];
    float* out = (float*)d_out;

    char* ws = (char*)d_ws;
    size_t o = 0;
    auto alloc = [&](size_t bytes) { void* p = ws + o; o += (bytes + 255) & ~(size_t)255; return p; };
    int*   nbr   = (int*)  alloc((size_t)NN * CAP * 4);
    int*   cnt   = (int*)  alloc((size_t)NN * 4);
    unsigned short* Whb = (unsigned short*)alloc((size_t)NN * HEADS * HID * 2);
    float* es4   = (float*)alloc((size_t)NN * 4 * 4);
    float* ed4   = (float*)alloc((size_t)NN * 4 * 4);
    float* Wh2   = (float*)alloc((size_t)NN * LAT * 4);
    float* es2   = (float*)alloc((size_t)NN * 4);
    float* ed2   = (float*)alloc((size_t)NN * 4);
    unsigned short* zh = (unsigned short*)alloc((size_t)NN * LAT * 2);
    unsigned short* zl = (unsigned short*)alloc((size_t)NN * LAT * 2);

    k_pre     <<<GEMM_BLOCKS + NN, 256, 0, stream>>>(A, x, Wheads, aheads, nbr, cnt, Whb, es4, ed4);
    k_attn1g2 <<<NN / 4, 256, 0, stream>>>(nbr, cnt, (const float4*)es4, (const float4*)ed4,
                                           Whb, Wout, aout, Wh2, es2, ed2);
    k_attn2   <<<NN / 4, 256, 0, stream>>>(nbr, cnt, es2, ed2, Wh2, zh, zl);
    k_zzt     <<<dim3(NN / 64, NN / 64), 256, 0, stream>>>(zh, zl, out);
}

// Round 13
// 113.629 us; speedup vs baseline: 1.8134x; 1.0080x over previous
//
#include <hip/hip_runtime.h>
#include <hip/hip_bf16.h>

#define NN 6144
#define IN_DIM 256
#define HID 64
#define HEADS 4
#define LAT 32
#define CAP 192
#define ALPHA 0.2f
#define GEMM_BLOCKS 384                  // (NN/64) * HEADS

typedef __attribute__((ext_vector_type(8))) short bf16x8;
typedef __attribute__((ext_vector_type(4))) float f32x4;

__device__ __forceinline__ float elu_f(float v)   { return v > 0.f ? v : expm1f(v); }
__device__ __forceinline__ float lrelu_f(float v) { return v > 0.f ? v : ALPHA * v; }

__device__ __forceinline__ void split_bf16(float v, unsigned short& hi, unsigned short& lo) {
    unsigned u = __builtin_bit_cast(unsigned, v);
    hi = (unsigned short)(u >> 16);
    float vh = __builtin_bit_cast(float, u & 0xFFFF0000u);
    float rl = v - vh;                       // exact
    lo = (unsigned short)(__builtin_bit_cast(unsigned, rl) >> 16);
}
__device__ __forceinline__ unsigned short f2bf(float f) {      // round-to-nearest-even
    unsigned u = __builtin_bit_cast(unsigned, f);
    return (unsigned short)((u + 0x7FFFu + ((u >> 16) & 1u)) >> 16);
}
__device__ __forceinline__ float bf2f(unsigned short b) {
    return __builtin_bit_cast(float, (unsigned)b << 16);
}

// ---------------- k_pre: gemm1(+es4/ed4 epilogue, bf16 Wh out) blocks first, then A-scan ----------------
__global__ __launch_bounds__(256) void k_pre(const float* __restrict__ A,
                                             const float* __restrict__ x,
                                             const float* __restrict__ Wheads,
                                             const float* __restrict__ aheads,
                                             int* __restrict__ nbr, int* __restrict__ cnt,
                                             unsigned short* __restrict__ Whb,
                                             float* __restrict__ es4, float* __restrict__ ed4) {
    __shared__ __align__(16) float smem[2048];   // 8 KB
    int bid = blockIdx.x;
    int t = threadIdx.x;
    if (bid < GEMM_BLOCKS) {
        int head = bid & 3, m0 = (bid >> 2) * 64;
        float (*As)[64] = (float(*)[64])smem;
        float (*Bs)[64] = (float(*)[64])(smem + 1024);
        const float* Wc = Wheads + (size_t)head * IN_DIM * HID;
        int ty = t >> 4, tx = t & 15;
        float acc[4][4] = {};
        for (int k0 = 0; k0 < IN_DIM; k0 += 16) {
            {
                int row = t >> 2, k4 = (t & 3) * 4;
                float4 v = *(const float4*)(x + (size_t)(m0 + row) * IN_DIM + k0 + k4);
                As[k4 + 0][row] = v.x; As[k4 + 1][row] = v.y;
                As[k4 + 2][row] = v.z; As[k4 + 3][row] = v.w;
                int kk = t >> 4, n4 = (t & 15) * 4;
                *(float4*)&Bs[kk][n4] = *(const float4*)(Wc + (size_t)(k0 + kk) * HID + n4);
            }
            __syncthreads();
            #pragma unroll
            for (int k = 0; k < 16; ++k) {
                float4 av = *(float4*)&As[k][ty * 4];
                float4 bv = *(float4*)&Bs[k][tx * 4];
                float ar[4] = {av.x, av.y, av.z, av.w};
                float br[4] = {bv.x, bv.y, bv.z, bv.w};
                #pragma unroll
                for (int i = 0; i < 4; ++i)
                    #pragma unroll
                    for (int j = 0; j < 4; ++j)
                        acc[i][j] = fmaf(ar[i], br[j], acc[i][j]);
            }
            __syncthreads();
        }
        #pragma unroll
        for (int i = 0; i < 4; ++i) {
            ushort4 o;
            o.x = f2bf(acc[i][0]); o.y = f2bf(acc[i][1]);
            o.z = f2bf(acc[i][2]); o.w = f2bf(acc[i][3]);
            *(ushort4*)(Whb + (size_t)(m0 + ty * 4 + i) * (HEADS * HID) + head * HID + tx * 4) = o;
        }
        float4 a1v = *(const float4*)(aheads + head * 2 * HID + tx * 4);
        float4 a2v = *(const float4*)(aheads + head * 2 * HID + HID + tx * 4);
        #pragma unroll
        for (int i = 0; i < 4; ++i) {
            float p1 = acc[i][0] * a1v.x + acc[i][1] * a1v.y + acc[i][2] * a1v.z + acc[i][3] * a1v.w;
            float p2 = acc[i][0] * a2v.x + acc[i][1] * a2v.y + acc[i][2] * a2v.z + acc[i][3] * a2v.w;
            #pragma unroll
            for (int off = 8; off; off >>= 1) {
                p1 += __shfl_down(p1, off, 16);
                p2 += __shfl_down(p2, off, 16);
            }
            if (tx == 0) {
                es4[(size_t)(m0 + ty * 4 + i) * 4 + head] = p1;   // [row][head]
                ed4[(size_t)(m0 + ty * 4 + i) * 4 + head] = p2;
            }
        }
    } else {
        int row = bid - GEMM_BLOCKS;
        int* lcnt = (int*)smem;
        const float4* Arow = (const float4*)(A + (size_t)row * NN);
        if (t == 0) *lcnt = 0;
        __syncthreads();
        int* my = nbr + (size_t)row * CAP;
        #pragma unroll
        for (int it = 0; it < NN / 4 / 256; ++it) {
            int idx4 = it * 256 + t;
            float4 v = Arow[idx4];
            int base = idx4 * 4;
            if (v.x != 0.f) { int p = atomicAdd(lcnt, 1); if (p < CAP) my[p] = base; }
            if (v.y != 0.f) { int p = atomicAdd(lcnt, 1); if (p < CAP) my[p] = base + 1; }
            if (v.z != 0.f) { int p = atomicAdd(lcnt, 1); if (p < CAP) my[p] = base + 2; }
            if (v.w != 0.f) { int p = atomicAdd(lcnt, 1); if (p < CAP) my[p] = base + 3; }
        }
        __syncthreads();
        if (t == 0) cnt[row] = *lcnt < CAP ? *lcnt : CAP;
    }
}

// ---------------- k_attn1g2: 4 rows/block, one wave per row (all 4 heads), 8-deep PV gather ILP ----------------
__global__ __launch_bounds__(256, 4) void k_attn1g2(const int* __restrict__ nbr, const int* __restrict__ cnt,
                                                    const float4* __restrict__ es4, const float4* __restrict__ ed4,
                                                    const unsigned short* __restrict__ Whb,
                                                    const float* __restrict__ Wout, const float* __restrict__ aout,
                                                    float* __restrict__ Wh2,
                                                    float* __restrict__ es2, float* __restrict__ ed2) {
    __shared__ int colS[4][CAP];                 // 3 KB
    __shared__ __align__(16) float att4[4][CAP][4];  // [row][j][head] 12 KB
    __shared__ __align__(16) float hrow[4][HEADS * HID]; // 4 KB
    int w = threadIdx.x >> 6, l = threadIdx.x & 63;
    int i = blockIdx.x * 4 + w;
    int c = cnt[i];
    const int* nb = nbr + (size_t)i * CAP;

    // phase 1: neighbor list + e (all 4 heads per lane), track per-head max
    float4 esv = es4[i];
    float m0 = -3.0e38f, m1 = -3.0e38f, m2 = -3.0e38f, m3 = -3.0e38f;
    for (int j = l; j < c; j += 64) {
        int cj = nb[j];
        colS[w][j] = cj;
        float4 edv = ed4[cj];
        float4 e;
        e.x = lrelu_f(esv.x + edv.x); e.y = lrelu_f(esv.y + edv.y);
        e.z = lrelu_f(esv.z + edv.z); e.w = lrelu_f(esv.w + edv.w);
        *(float4*)&att4[w][j][0] = e;
        m0 = fmaxf(m0, e.x); m1 = fmaxf(m1, e.y);
        m2 = fmaxf(m2, e.z); m3 = fmaxf(m3, e.w);
    }
    #pragma unroll
    for (int off = 32; off; off >>= 1) {
        m0 = fmaxf(m0, __shfl_down(m0, off)); m1 = fmaxf(m1, __shfl_down(m1, off));
        m2 = fmaxf(m2, __shfl_down(m2, off)); m3 = fmaxf(m3, __shfl_down(m3, off));
    }
    m0 = __shfl(m0, 0); m1 = __shfl(m1, 0); m2 = __shfl(m2, 0); m3 = __shfl(m3, 0);
    // phase 2: exp + per-head sum
    float s0 = 0.f, s1 = 0.f, s2 = 0.f, s3 = 0.f;
    for (int j = l; j < c; j += 64) {
        float4 e = *(float4*)&att4[w][j][0];
        e.x = __expf(e.x - m0); e.y = __expf(e.y - m1);
        e.z = __expf(e.z - m2); e.w = __expf(e.w - m3);
        *(float4*)&att4[w][j][0] = e;
        s0 += e.x; s1 += e.y; s2 += e.z; s3 += e.w;
    }
    #pragma unroll
    for (int off = 32; off; off >>= 1) {
        s0 += __shfl_down(s0, off); s1 += __shfl_down(s1, off);
        s2 += __shfl_down(s2, off); s3 += __shfl_down(s3, off);
    }
    s0 = __shfl(s0, 0); s1 = __shfl(s1, 0); s2 = __shfl(s2, 0); s3 = __shfl(s3, 0);
    __syncthreads();   // att4/colS visible (cross-lane)

    // phase 3: PV — lane l gathers ushort4 (cols 4l..4l+3); 8 independent chains
    int hd = l >> 4;
    float sh = hd < 2 ? (hd == 0 ? s0 : s1) : (hd == 2 ? s2 : s3);
    float invh = 1.0f / sh;
    float4 hv;
    if (c == 0) {   // deg==0 fallback: column means (never taken w.h.p.)
        float a0 = 0.f, a1 = 0.f, a2 = 0.f, a3 = 0.f;
        for (int r = 0; r < NN; ++r) {
            ushort4 v = *(const ushort4*)(Whb + (size_t)r * (HEADS * HID) + 4 * l);
            a0 += bf2f(v.x); a1 += bf2f(v.y); a2 += bf2f(v.z); a3 += bf2f(v.w);
        }
        hv.x = elu_f(a0 / NN); hv.y = elu_f(a1 / NN);
        hv.z = elu_f(a2 / NN); hv.w = elu_f(a3 / NN);
    } else {
        const unsigned short* Wb = Whb + 4 * l;
        float ax[8], ay[8], az[8], aw[8];
        #pragma unroll
        for (int k = 0; k < 8; ++k) { ax[k] = 0.f; ay[k] = 0.f; az[k] = 0.f; aw[k] = 0.f; }
        int j = 0;
        for (; j + 8 <= c; j += 8) {
            int cj[8]; float ff[8]; ushort4 vv[8];
            #pragma unroll
            for (int k = 0; k < 8; ++k) { cj[k] = colS[w][j + k]; ff[k] = att4[w][j + k][hd]; }
            #pragma unroll
            for (int k = 0; k < 8; ++k) vv[k] = *(const ushort4*)(Wb + (size_t)cj[k] * (HEADS * HID));
            #pragma unroll
            for (int k = 0; k < 8; ++k) {
                ax[k] = fmaf(ff[k], bf2f(vv[k].x), ax[k]);
                ay[k] = fmaf(ff[k], bf2f(vv[k].y), ay[k]);
                az[k] = fmaf(ff[k], bf2f(vv[k].z), az[k]);
                aw[k] = fmaf(ff[k], bf2f(vv[k].w), aw[k]);
            }
        }
        for (; j < c; ++j) {
            int cj = colS[w][j];
            float f = att4[w][j][hd];
            ushort4 v = *(const ushort4*)(Wb + (size_t)cj * (HEADS * HID));
            ax[0] = fmaf(f, bf2f(v.x), ax[0]); ay[0] = fmaf(f, bf2f(v.y), ay[0]);
            az[0] = fmaf(f, bf2f(v.z), az[0]); aw[0] = fmaf(f, bf2f(v.w), aw[0]);
        }
        float rx = ((ax[0] + ax[1]) + (ax[2] + ax[3])) + ((ax[4] + ax[5]) + (ax[6] + ax[7]));
        float ry = ((ay[0] + ay[1]) + (ay[2] + ay[3])) + ((ay[4] + ay[5]) + (ay[6] + ay[7]));
        float rz = ((az[0] + az[1]) + (az[2] + az[3])) + ((az[4] + az[5]) + (az[6] + az[7]));
        float rw = ((aw[0] + aw[1]) + (aw[2] + aw[3])) + ((aw[4] + aw[5]) + (aw[6] + aw[7]));
        hv.x = elu_f(rx * invh); hv.y = elu_f(ry * invh);
        hv.z = elu_f(rz * invh); hv.w = elu_f(rw * invh);
    }
    *(float4*)&hrow[w][4 * l] = hv;
    __syncthreads();

    // phase 4: gemm2 — wave w computes Wh2[i,:]; 2 lanes per col, 128-deep each
    {
        int half = l >> 5, cc = l & 31;
        int tbase = half * 128;
        float p = 0.f;
        #pragma unroll 8
        for (int tt = 0; tt < 128; ++tt)
            p = fmaf(hrow[w][tbase + tt], Wout[(tbase + tt) * LAT + cc], p);
        p += __shfl_down(p, 32);
        if (l < 32) {
            Wh2[(size_t)i * LAT + cc] = p;
            float p1 = p * aout[cc], p2 = p * aout[LAT + cc];
            #pragma unroll
            for (int off = 16; off; off >>= 1) {
                p1 += __shfl_down(p1, off, 32);
                p2 += __shfl_down(p2, off, 32);
            }
            if (cc == 0) { es2[i] = p1; ed2[i] = p2; }
        }
    }
}

// ---------------- attention layer 2 -> z (split bf16 out), 4 rows per block ----------------
__global__ __launch_bounds__(256, 8) void k_attn2(const int* __restrict__ nbr, const int* __restrict__ cnt,
                                                  const float* __restrict__ es2, const float* __restrict__ ed2,
                                                  const float* __restrict__ Wh2,
                                                  unsigned short* __restrict__ zh, unsigned short* __restrict__ zl) {
    __shared__ float att[4][CAP];
    __shared__ int col[4][CAP];
    int w = threadIdx.x >> 6, l = threadIdx.x & 63;
    int i = blockIdx.x * 4 + w;
    int c = cnt[i];
    if (c == 0) {
        if (l < LAT) {
            float s = 0.f;
            for (int r = 0; r < NN; ++r) s += Wh2[(size_t)r * LAT + l];
            unsigned short hi, lo;
            split_bf16(elu_f(s * (1.0f / NN)), hi, lo);
            zh[(size_t)i * LAT + l] = hi;
            zl[(size_t)i * LAT + l] = lo;
        }
        return;
    }
    float esi = es2[i];
    const int* nb = nbr + (size_t)i * CAP;
    float m = -3.0e38f;
    for (int j = l; j < c; j += 64) {
        int cj = nb[j];
        col[w][j] = cj;
        float e = lrelu_f(esi + ed2[cj]);
        att[w][j] = e;
        m = fmaxf(m, e);
    }
    #pragma unroll
    for (int off = 32; off; off >>= 1) m = fmaxf(m, __shfl_down(m, off));
    m = __shfl(m, 0);
    float s = 0.f;
    for (int j = l; j < c; j += 64) {
        float p = __expf(att[w][j] - m);
        att[w][j] = p;
        s += p;
    }
    #pragma unroll
    for (int off = 32; off; off >>= 1) s += __shfl_down(s, off);
    s = __shfl(s, 0);
    if (l < LAT) {
        float inv = 1.0f / s;
        float a0 = 0.f, a1 = 0.f, a2 = 0.f, a3 = 0.f;
        int j = 0;
        for (; j + 4 <= c; j += 4) {
            a0 = fmaf(att[w][j + 0], Wh2[(size_t)col[w][j + 0] * LAT + l], a0);
            a1 = fmaf(att[w][j + 1], Wh2[(size_t)col[w][j + 1] * LAT + l], a1);
            a2 = fmaf(att[w][j + 2], Wh2[(size_t)col[w][j + 2] * LAT + l], a2);
            a3 = fmaf(att[w][j + 3], Wh2[(size_t)col[w][j + 3] * LAT + l], a3);
        }
        for (; j < c; ++j)
            a0 = fmaf(att[w][j], Wh2[(size_t)col[w][j] * LAT + l], a0);
        unsigned short hi, lo;
        split_bf16(elu_f(((a0 + a1) + (a2 + a3)) * inv), hi, lo);
        zh[(size_t)i * LAT + l] = hi;
        zl[(size_t)i * LAT + l] = lo;
    }
}

// ---------------- out = sigmoid(z @ z^T) via split-bf16 MFMA, symmetric float4 stores ----------------
__global__ __launch_bounds__(256, 8) void k_zzt(const unsigned short* __restrict__ zh,
                                                const unsigned short* __restrict__ zl,
                                                float* __restrict__ out) {
    int t = threadIdx.x, w = t >> 6, l = t & 63;
    int m0 = blockIdx.y * 64 + w * 16;
    int n0 = blockIdx.x * 64;
    int r = l & 15, kg = (l >> 4) * 8;   // lane row-in-tile, k-group of 8
    bf16x8 ah = *(const bf16x8*)(zh + (size_t)(m0 + r) * LAT + kg);
    bf16x8 al = *(const bf16x8*)(zl + (size_t)(m0 + r) * LAT + kg);
    int mbase = m0 + (l >> 4) * 4;       // 4 consecutive C-rows this lane owns
    #pragma unroll
    for (int jp = 0; jp < 2; ++jp) {
        int nbA = n0 + (jp * 2 + 0) * 16;
        int nbB = n0 + (jp * 2 + 1) * 16;
        bf16x8 bhA = *(const bf16x8*)(zh + (size_t)(nbA + r) * LAT + kg);
        bf16x8 blA = *(const bf16x8*)(zl + (size_t)(nbA + r) * LAT + kg);
        bf16x8 bhB = *(const bf16x8*)(zh + (size_t)(nbB + r) * LAT + kg);
        bf16x8 blB = *(const bf16x8*)(zl + (size_t)(nbB + r) * LAT + kg);
        f32x4 accA = {0.f, 0.f, 0.f, 0.f};
        accA = __builtin_amdgcn_mfma_f32_16x16x32_bf16(ah, bhA, accA, 0, 0, 0);
        accA = __builtin_amdgcn_mfma_f32_16x16x32_bf16(ah, blA, accA, 0, 0, 0);
        accA = __builtin_amdgcn_mfma_f32_16x16x32_bf16(al, bhA, accA, 0, 0, 0);
        f32x4 accB = {0.f, 0.f, 0.f, 0.f};
        accB = __builtin_amdgcn_mfma_f32_16x16x32_bf16(ah, bhB, accB, 0, 0, 0);
        accB = __builtin_amdgcn_mfma_f32_16x16x32_bf16(ah, blB, accB, 0, 0, 0);
        accB = __builtin_amdgcn_mfma_f32_16x16x32_bf16(al, bhB, accB, 0, 0, 0);
        float4 oA, oB;
        oA.x = 1.0f / (1.0f + __expf(-accA[0]));
        oA.y = 1.0f / (1.0f + __expf(-accA[1]));
        oA.z = 1.0f / (1.0f + __expf(-accA[2]));
        oA.w = 1.0f / (1.0f + __expf(-accA[3]));
        oB.x = 1.0f / (1.0f + __expf(-accB[0]));
        oB.y = 1.0f / (1.0f + __expf(-accB[1]));
        oB.z = 1.0f / (1.0f + __expf(-accB[2]));
        oB.w = 1.0f / (1.0f + __expf(-accB[3]));
        // transposed store via output symmetry: out[col][mbase..mbase+3]
        *(float4*)(out + (size_t)(nbA + (l & 15)) * NN + mbase) = oA;
        *(float4*)(out + (size_t)(nbB + (l & 15)) * NN + mbase) = oB;
    }
}

extern "C" void kernel_launch(void* const* d_in, const int* in_sizes, int n_in,
                              void* d_out, int out_size, void* d_ws, size_t ws_size,
                              hipStream_t stream) {
    const float* x      = (const float*)d_in[0];
    const float* A      = (const float*)d_in[1];
    const float* Wheads = (const float*)d_in[2];
    const float* aheads = (const float*)d_in[3];
    const float* Wout   = (const float*)d_in[4];
    const float* aout   = (const float*)d_in[5];
    float* out = (float*)d_out;

    char* ws = (char*)d_ws;
    size_t o = 0;
    auto alloc = [&](size_t bytes) { void* p = ws + o; o += (bytes + 255) & ~(size_t)255; return p; };
    int*   nbr   = (int*)  alloc((size_t)NN * CAP * 4);
    int*   cnt   = (int*)  alloc((size_t)NN * 4);
    unsigned short* Whb = (unsigned short*)alloc((size_t)NN * HEADS * HID * 2);
    float* es4   = (float*)alloc((size_t)NN * 4 * 4);
    float* ed4   = (float*)alloc((size_t)NN * 4 * 4);
    float* Wh2   = (float*)alloc((size_t)NN * LAT * 4);
    float* es2   = (float*)alloc((size_t)NN * 4);
    float* ed2   = (float*)alloc((size_t)NN * 4);
    unsigned short* zh = (unsigned short*)alloc((size_t)NN * LAT * 2);
    unsigned short* zl = (unsigned short*)alloc((size_t)NN * LAT * 2);

    k_pre     <<<GEMM_BLOCKS + NN, 256, 0, stream>>>(A, x, Wheads, aheads, nbr, cnt, Whb, es4, ed4);
    k_attn1g2 <<<NN / 4, 256, 0, stream>>>(nbr, cnt, (const float4*)es4, (const float4*)ed4,
                                           Whb, Wout, aout, Wh2, es2, ed2);
    k_attn2   <<<NN / 4, 256, 0, stream>>>(nbr, cnt, es2, ed2, Wh2, zh, zl);
    k_zzt     <<<dim3(NN / 64, NN / 64), 256, 0, stream>>>(zh, zl, out);
}